// Round 1
// 2898.187 us; speedup vs baseline: 1.5145x; 1.5145x over previous
//
#include <hip/hip_runtime.h>

typedef unsigned short u16;
typedef short short8 __attribute__((ext_vector_type(8)));
typedef float f32x4 __attribute__((ext_vector_type(4)));
typedef unsigned short u16x4 __attribute__((ext_vector_type(4)));

#define B_  256
#define T_  600
#define TC_ 75    // time chunk (8 chunks; halved so two xg buffers fit old footprint)
#define HID 200
#define G4  800
#define HSTR 232  // hbuf row stride (u16): 464B = 16 mod 32 dwords -> uniform banks

__device__ __forceinline__ float bf2f(u16 u) {
  union { unsigned int i; float f; } v; v.i = ((unsigned int)u) << 16; return v.f;
}
__device__ __forceinline__ u16 f2bf(float f) {
  union { float f; unsigned int i; } v; v.f = f;
  unsigned int r = v.i + 0x7FFFu + ((v.i >> 16) & 1u);
  return (u16)(r >> 16);
}
__device__ __forceinline__ float sigm(float x) {
  float e = __expf(-x);
  return __builtin_amdgcn_rcpf(1.f + e);
}

// sync_a: LDS writes must be visible; global ops may remain in flight.
#define BARRIER_LGKM() asm volatile("s_waitcnt lgkmcnt(0)\n\ts_barrier" ::: "memory")
// sync_b: all LDS reads already register-consumed; just rendezvous.
#define BARRIER_ONLY() asm volatile("s_barrier" ::: "memory")

// ---------------------------------------------------------------------------
// Pad / permute / downcast f32 weights into aligned bf16 scratch.
// ---------------------------------------------------------------------------
__global__ __launch_bounds__(256) void padperm_k(const float* __restrict__ src,
                                                 u16* __restrict__ dst,
                                                 int rows, int srows, int scols,
                                                 int dcols, int perm) {
  int idx = blockIdx.x * 256 + threadIdx.x;
  if (idx >= rows * dcols) return;
  int r = idx / dcols, c = idx - r * dcols;
  int sr = perm ? ((r & 3) * 200 + (r >> 2)) : r;
  dst[idx] = (r < srows && c < scols) ? f2bf(src[(size_t)sr * scols + c]) : (u16)0;
}

// ---------------------------------------------------------------------------
// Transpose chunk: x [B][129][600] f32 -> xTq [B][TC_][160] bf16, window t0.
// ---------------------------------------------------------------------------
__global__ __launch_bounds__(256) void transpose_k(const float* __restrict__ x,
                                                   u16* __restrict__ xTq, int t0) {
  __shared__ u16 tile[129 * 65];
  const int b = blockIdx.y;
  const int tt0 = blockIdx.x * 64;
  const int tid = threadIdx.x;
  for (int idx = tid; idx < 129 * 64; idx += 256) {
    int i = idx >> 6, tt = idx & 63;
    int t = t0 + tt0 + tt;
    tile[i * 65 + tt] = (tt0 + tt < TC_ && t < T_)
        ? f2bf(x[((size_t)b * 129 + i) * T_ + t]) : (u16)0;
  }
  __syncthreads();
  for (int idx = tid; idx < 64 * 160; idx += 256) {
    int tt = idx / 160, i = idx - tt * 160;
    if (tt0 + tt < TC_)
      xTq[((size_t)b * TC_ + tt0 + tt) * 160 + i] = (i < 129) ? tile[i * 65 + tt] : (u16)0;
  }
}

// ---------------------------------------------------------------------------
// GEMM: out = ACT(A @ W^T + bias).
// ---------------------------------------------------------------------------
template<int ASRC, int LDK, int NSRC, int NSTORE, int BPERM, int ACT, int OUTM, int CHUNK>
__global__ __launch_bounds__(256, 2) void gemm_k(
    const u16* __restrict__ A, const u16* __restrict__ W,
    const float* __restrict__ B1, const float* __restrict__ B2,
    void* __restrict__ outv, int ldout, int t0) {
  constexpr int NCH = LDK / 8;
  constexpr int KT = LDK / 32;
  __shared__ u16 la[128 * LDK];
  __shared__ float lbias[128];
  const int tid = threadIdx.x;
  const int mb = blockIdx.x, nb = blockIdx.y;

  for (int idx = tid; idx < 128 * NCH; idx += 256) {
    int row = idx / NCH, c = idx - row * NCH;
    int m = mb * 128 + row;
    size_t arow;
    if (CHUNK) {
      int b = m / TC_;
      int tt = m - b * TC_;
      arow = (size_t)b * T_ + t0 + tt;
    } else {
      arow = (size_t)m;
    }
    short8 v = (short8)0;
    if (8 * c + 8 <= ASRC)
      v = *(const short8*)(A + arow * ASRC + 8 * c);
    *(short8*)(la + row * LDK + 8 * c) = v;
  }
  if (tid < 128) {
    int p = nb * 128 + tid;
    float bv = 0.f;
    if (p < NSRC) {
      int orig = BPERM ? ((p & 3) * 200 + (p >> 2)) : p;
      bv = B1[orig];
      if (BPERM) bv += B2[orig];
    }
    lbias[tid] = bv;
  }
  __syncthreads();

  const int w = tid >> 6, l = tid & 63;
  const int quad = l >> 4, l15 = l & 15;
  const int mq = (w >> 1) * 64, nq = (w & 1) * 64;

  const u16* wrow[4];
#pragma unroll
  for (int nt = 0; nt < 4; ++nt) {
    int p = nb * 128 + nq + nt * 16 + l15;
    wrow[nt] = W + (size_t)((p < NSRC) ? p : 0) * LDK;
  }

  f32x4 acc[4][4];
#pragma unroll
  for (int i = 0; i < 4; ++i)
#pragma unroll
    for (int j = 0; j < 4; ++j) acc[i][j] = (f32x4)0.f;

#pragma unroll
  for (int kt = 0; kt < KT; ++kt) {
    const int k0 = kt * 32 + quad * 8;
    short8 bf[4];
#pragma unroll
    for (int nt = 0; nt < 4; ++nt) bf[nt] = *(const short8*)(wrow[nt] + k0);
    short8 af[4];
#pragma unroll
    for (int mt = 0; mt < 4; ++mt)
      af[mt] = *(const short8*)(la + (mq + mt * 16 + l15) * LDK + k0);
#pragma unroll
    for (int mt = 0; mt < 4; ++mt)
#pragma unroll
      for (int nt = 0; nt < 4; ++nt)
        acc[mt][nt] = __builtin_amdgcn_mfma_f32_16x16x32_bf16(af[mt], bf[nt],
                                                              acc[mt][nt], 0, 0, 0);
  }

#pragma unroll
  for (int mt = 0; mt < 4; ++mt) {
#pragma unroll
    for (int nt = 0; nt < 4; ++nt) {
#pragma unroll
      for (int r = 0; r < 4; ++r) {
        int rowl = mq + mt * 16 + quad * 4 + r;
        int coln = nq + nt * 16 + l15;
        int pg = nb * 128 + coln;
        if (pg < NSTORE) {
          float v = (pg < NSRC) ? (acc[mt][nt][r] + lbias[coln]) : 0.f;
          if (ACT == 1) v = fmaxf(v, 0.f);
          if (ACT == 2) v = sigm(v);
          size_t m = (size_t)mb * 128 + rowl;
          if (OUTM == 0) {
            ((u16*)outv)[m * (size_t)ldout + pg] = f2bf(v);
          } else {
            int b = (int)(m / T_);
            int t = (int)(m - (size_t)b * T_);
            ((float*)outv)[((size_t)b * 129 + pg) * T_ + t] = v;
          }
        }
      }
    }
  }
}

// ---------------------------------------------------------------------------
// Persistent LSTM recurrence over one time chunk [t0, t0+TC_), one 16-batch
// group per workgroup (blk). Body identical to the verified rec_k; hoisted so
// two independent parameter sets (layer-1 chunk i+1 / layer-2 chunk i) can be
// dispatched in ONE launch on disjoint CUs -> software pipeline across layers.
// ---------------------------------------------------------------------------
__device__ __forceinline__ void rec_body(const u16* __restrict__ xgq,
                                         const u16* __restrict__ whh,
                                         u16* __restrict__ hout,
                                         float* __restrict__ cst,
                                         int t0, int blk) {
  __shared__ u16 hbuf[16 * HSTR];    // 7424 B  h[batch][unit], cols 200..231 = 0
  __shared__ u16 w6lds[50 * 128];    // 12800 B kt6 fragments, 16 lanes x 16B/tile

  const int tid = threadIdx.x;
  const int w = tid >> 6, l = tid & 63;
  const int quad = l >> 4, l15 = l & 15;
  const int b0 = blk * 16;
  const int nslots = (w < 2) ? 7 : 6;   // 50 N-tiles over 8 waves

  // ---- prologue: weight caches ----
  short8 wreg[7][6];                    // k-tiles 0..5
#pragma unroll
  for (int s = 0; s < 7; ++s) {
    int p = (w + 8 * s) * 16 + l15;
    int orig = (p & 3) * 200 + (p >> 2);
    const char* wbase = (const char*)whh + (size_t)orig * 400;
#pragma unroll
    for (int kk = 0; kk < 6; ++kk) {
      short8 v = (short8)0;
      if (s < nslots)
        v = *(const short8*)(wbase + kk * 64 + quad * 16);
      wreg[s][kk] = v;
    }
    // kt6 compact: quad0 lanes stash k=192..199 (last 16B of the row)
    if (s < nslots && quad == 0) {
      short8 v6 = *(const short8*)(wbase + 384);
      *(short8*)(w6lds + (w + 8 * s) * 128 + l15 * 8) = v6;
    }
  }
  for (int i = tid; i < 16 * HSTR; i += 512) hbuf[i] = 0;

  // ---- state: slot s -> (batch l15, unit (w+8s)*4+quad) ----
  float c[7];
  u16 hreg[7];
#pragma unroll
  for (int s = 0; s < 7; ++s) { c[s] = 0.f; hreg[s] = 0; }
  if (t0 != 0) {
#pragma unroll
    for (int s = 0; s < 7; ++s)
      if (s < nslots) {
        int unit = (w + 8 * s) * 4 + quad;
        hreg[s] = hout[((size_t)(b0 + l15) * T_ + (t0 - 1)) * HID + unit];
        c[s] = cst[(size_t)(b0 + l15) * HID + unit];
      }
  }

  // per-lane xg gather base (t=0 of this chunk) + first prefetch
  const u16* xptr = xgq + (size_t)(b0 + l15) * TC_ * G4 + w * 16 + quad * 4;
  u16x4 xv[7];
#pragma unroll
  for (int s = 0; s < 7; ++s)
    xv[s] = (s < nslots) ? *(const u16x4*)(xptr + s * 128) : (u16x4)0;

  // per-lane hout base for unit stores
  u16* hptr = hout + ((size_t)(b0 + l15) * T_ + t0) * HID;

  __syncthreads();  // prologue fence (w6lds + hbuf zeros visible)

  for (int t = 0; t < TC_; ++t) {
    // publish h(t-1) to LDS
#pragma unroll
    for (int s = 0; s < 7; ++s)
      if (s < nslots)
        hbuf[l15 * HSTR + (w + 8 * s) * 4 + quad] = hreg[s];
    BARRIER_LGKM();  // sync_a

    // deferred global h(t-1) store (stays in flight across barriers)
    if (t > 0) {
#pragma unroll
      for (int s = 0; s < 7; ++s)
        if (s < nslots)
          hptr[(size_t)(t - 1) * HID + (w + 8 * s) * 4 + quad] = hreg[s];
    }

    // ---- gates^T = Whh_perm @ h(t-1)^T ----
    f32x4 acc[7];
#pragma unroll
    for (int s = 0; s < 7; ++s) acc[s] = (f32x4)0.f;
#pragma unroll
    for (int kk = 0; kk < 6; ++kk) {
      short8 hf = *(const short8*)(hbuf + l15 * HSTR + kk * 32 + quad * 8);
#pragma unroll
      for (int s = 0; s < 7; ++s)
        if (s < nslots)
          acc[s] = __builtin_amdgcn_mfma_f32_16x16x32_bf16(wreg[s][kk], hf, acc[s], 0, 0, 0);
    }
    {  // tail k-tile 6: h cols 192..199 real, 200..223 zero-padded
      short8 hf = *(const short8*)(hbuf + l15 * HSTR + 192 + quad * 8);
#pragma unroll
      for (int s = 0; s < 7; ++s)
        if (s < nslots) {
          short8 wz = (short8)0;
          if (quad == 0)
            wz = *(const short8*)(w6lds + (w + 8 * s) * 128 + l15 * 8);
          acc[s] = __builtin_amdgcn_mfma_f32_16x16x32_bf16(wz, hf, acc[s], 0, 0, 0);
        }
    }

    // ---- lane-local cell update: acc[s][0..3] = i,f,g,o pre-acts ----
#pragma unroll
    for (int s = 0; s < 7; ++s) {
      if (s < nslots) {
        float vi = acc[s][0] + bf2f(xv[s][0]);
        float vf = acc[s][1] + bf2f(xv[s][1]);
        float vg = acc[s][2] + bf2f(xv[s][2]);
        float vo = acc[s][3] + bf2f(xv[s][3]);
        float iv = sigm(vi);
        float fv = sigm(vf);
        float gv = 2.f * sigm(2.f * vg) - 1.f;  // tanh
        float ov = sigm(vo);
        float cn = fv * c[s] + iv * gv;
        c[s] = cn;
        float th = 2.f * sigm(2.f * cn) - 1.f;
        hreg[s] = f2bf(ov * th);
      }
    }

    // prefetch xg(t+1) into the (just-consumed) xv regs
    if (t + 1 < TC_) {
      const u16* xp = xptr + (size_t)(t + 1) * G4;
#pragma unroll
      for (int s = 0; s < 7; ++s)
        if (s < nslots) xv[s] = *(const u16x4*)(xp + s * 128);
    }
    BARRIER_ONLY();  // sync_b: all hbuf reads already register-consumed
  }

  // final h(t0+TC_-1) + carry state
#pragma unroll
  for (int s = 0; s < 7; ++s)
    if (s < nslots) {
      int unit = (w + 8 * s) * 4 + quad;
      hptr[(size_t)(TC_ - 1) * HID + unit] = hreg[s];
      cst[(size_t)(b0 + l15) * HID + unit] = c[s];
    }
}

// Fused dual-group recurrence: blocks [0,nA) run param set A (layer-1 chunk),
// blocks [nA,grid) run set B (layer-2 chunk) on other CUs, concurrently.
__global__ __launch_bounds__(512) void recp_k(
    const u16* __restrict__ xgA, const u16* __restrict__ whhA,
    u16* __restrict__ hA, float* __restrict__ cstA, int t0A,
    const u16* __restrict__ xgB, const u16* __restrict__ whhB,
    u16* __restrict__ hB, float* __restrict__ cstB, int t0B, int nA) {
  const int bb = blockIdx.x;
  const u16* xg; const u16* whh; u16* ho; float* cs; int t0, blk;
  if (bb < nA) { xg = xgA; whh = whhA; ho = hA; cs = cstA; t0 = t0A; blk = bb; }
  else         { xg = xgB; whh = whhB; ho = hB; cs = cstB; t0 = t0B; blk = bb - nA; }
  rec_body(xg, whh, ho, cs, t0, blk);
}

// ---------------------------------------------------------------------------
extern "C" void kernel_launch(void* const* d_in, const int* in_sizes, int n_in,
                              void* d_out, int out_size, void* d_ws, size_t ws_size,
                              hipStream_t stream) {
  (void)in_sizes; (void)n_in; (void)out_size; (void)ws_size;
  const float* x     = (const float*)d_in[0];
  const float* w_ih1 = (const float*)d_in[1];
  const float* w_hh1 = (const float*)d_in[2];
  const float* b_ih1 = (const float*)d_in[3];
  const float* b_hh1 = (const float*)d_in[4];
  const float* w_ih2 = (const float*)d_in[5];
  const float* w_hh2 = (const float*)d_in[6];
  const float* b_ih2 = (const float*)d_in[7];
  const float* b_hh2 = (const float*)d_in[8];
  const float* fc1_w = (const float*)d_in[9];
  const float* fc1_b = (const float*)d_in[10];
  const float* fc2_w = (const float*)d_in[11];
  const float* fc2_b = (const float*)d_in[12];
  float* out = (float*)d_out;

  // workspace layout (bytes, 16-aligned); total ~192.2 MB
  char* ws = (char*)d_ws;
  u16*   xgA   = (u16*)(ws);                     //  30,720,000  [256][75][800]
  u16*   xgB   = (u16*)(ws + 30720000LL);        //  30,720,000  [256][75][800]
  u16*   h1    = (u16*)(ws + 61440000LL);        //  61,440,000  [256][600][200]
  u16*   h2    = (u16*)(ws + 122880000LL);       //  61,440,000
  u16*   xTq   = (u16*)(ws + 184320000LL);       //   6,144,000  [256][75][160]
  float* cst1  = (float*)(ws + 190464000LL);     //     204,800  [256][200] f32
  float* cst2  = (float*)(ws + 190668800LL);     //     204,800
  u16*   wp1   = (u16*)(ws + 190873600LL);       //     256,000  [800][160]
  u16*   wp2   = (u16*)(ws + 191129600LL);       //     358,400  [800][224]
  u16*   fc1p  = (u16*)(ws + 191488000LL);       //      57,792  [129][224]
  u16*   fc2p  = (u16*)(ws + 191545792LL);       //      41,280  [129][160]
  u16*   whh1c = (u16*)(ws + 191587072LL);       //     320,000  [800][200]
  u16*   whh2c = (u16*)(ws + 191907072LL);       //     320,000  [800][200]
  u16*   y1    = h1;                             // reuse after layer-2 GEMMs

  padperm_k<<<(800 * 160 + 255) / 256, 256, 0, stream>>>(w_ih1, wp1, 800, 800, 129, 160, 1);
  padperm_k<<<(800 * 224 + 255) / 256, 256, 0, stream>>>(w_ih2, wp2, 800, 800, 200, 224, 1);
  padperm_k<<<(129 * 224 + 255) / 256, 256, 0, stream>>>(fc1_w, fc1p, 129, 129, 200, 224, 0);
  padperm_k<<<(129 * 160 + 255) / 256, 256, 0, stream>>>(fc2_w, fc2p, 129, 129, 129, 160, 0);
  padperm_k<<<(800 * 200 + 255) / 256, 256, 0, stream>>>(w_hh1, whh1c, 800, 800, 200, 200, 0);
  padperm_k<<<(800 * 200 + 255) / 256, 256, 0, stream>>>(w_hh2, whh2c, 800, 800, 200, 200, 0);

  // ---- software pipeline: rec1(c_{i+1}) runs concurrently with rec2(c_i) ----
  // stage 0: layer-1 chunk 0 alone
  transpose_k<<<dim3(2, 256), 256, 0, stream>>>(x, xTq, 0);
  gemm_k<160, 160, 800, 800, 1, 0, 0, 0>
      <<<dim3(150, 7), 256, 0, stream>>>(xTq, wp1, b_ih1, b_hh1, xgA, 800, 0);
  recp_k<<<dim3(16), 512, 0, stream>>>(xgA, whh1c, h1, cst1, 0,
                                       xgA, whh1c, h1, cst1, 0, 16);

  // stages 1..7: fused (layer-1 chunk i+1 || layer-2 chunk i)
  for (int i = 0; i < 7; ++i) {
    const int tA = (i + 1) * TC_;
    const int tB = i * TC_;
    transpose_k<<<dim3(2, 256), 256, 0, stream>>>(x, xTq, tA);
    gemm_k<160, 160, 800, 800, 1, 0, 0, 0>
        <<<dim3(150, 7), 256, 0, stream>>>(xTq, wp1, b_ih1, b_hh1, xgA, 800, 0);
    gemm_k<200, 224, 800, 800, 1, 0, 0, 1>
        <<<dim3(150, 7), 256, 0, stream>>>(h1, wp2, b_ih2, b_hh2, xgB, 800, tB);
    recp_k<<<dim3(32), 512, 0, stream>>>(xgA, whh1c, h1, cst1, tA,
                                         xgB, whh2c, h2, cst2, tB, 16);
  }

  // stage 8: layer-2 chunk 7 alone
  gemm_k<200, 224, 800, 800, 1, 0, 0, 1>
      <<<dim3(150, 7), 256, 0, stream>>>(h1, wp2, b_ih2, b_hh2, xgB, 800, 7 * TC_);
  recp_k<<<dim3(16), 512, 0, stream>>>(xgA, whh1c, h1, cst1, 0,
                                       xgB, whh2c, h2, cst2, 7 * TC_, 0);

  // y1 = relu(h2 @ fc1^T + b)
  gemm_k<200, 224, 129, 144, 0, 1, 0, 0>
      <<<dim3(1200, 2), 256, 0, stream>>>(h2, fc1p, fc1_b, fc1_b, y1, 144, 0);
  // out = sigmoid(y1 @ fc2^T + b), f32 scatter to [B][129][T]
  gemm_k<144, 160, 129, 129, 0, 2, 1, 0>
      <<<dim3(1200, 2), 256, 0, stream>>>(y1, fc2p, fc2_b, fc2_b, out, 0, 0);
}

// Round 2
// 2759.035 us; speedup vs baseline: 1.5908x; 1.0504x over previous
//
#include <hip/hip_runtime.h>

typedef unsigned short u16;
typedef short short8 __attribute__((ext_vector_type(8)));
typedef float f32x4 __attribute__((ext_vector_type(4)));
typedef unsigned short u16x4 __attribute__((ext_vector_type(4)));

#define B_  256
#define T_  600
#define TC_ 75    // time chunk (8 chunks; two xg buffers ping-pong)
#define HID 200
#define G4  800
#define HSTR 232  // hbuf row stride (u16): 464B = 16 mod 32 dwords -> uniform banks

__device__ __forceinline__ float bf2f(u16 u) {
  union { unsigned int i; float f; } v; v.i = ((unsigned int)u) << 16; return v.f;
}
__device__ __forceinline__ u16 f2bf(float f) {
  union { float f; unsigned int i; } v; v.f = f;
  unsigned int r = v.i + 0x7FFFu + ((v.i >> 16) & 1u);
  return (u16)(r >> 16);
}
__device__ __forceinline__ float sigm(float x) {
  float e = __expf(-x);
  return __builtin_amdgcn_rcpf(1.f + e);
}

// sync_a: LDS writes must be visible; global ops may remain in flight.
#define BARRIER_LGKM() asm volatile("s_waitcnt lgkmcnt(0)\n\ts_barrier" ::: "memory")
// sync_b: all LDS reads already register-consumed; just rendezvous.
#define BARRIER_ONLY() asm volatile("s_barrier" ::: "memory")

// ---------------------------------------------------------------------------
// Pad / permute / downcast f32 weights into aligned bf16 scratch.
// ---------------------------------------------------------------------------
__global__ __launch_bounds__(256) void padperm_k(const float* __restrict__ src,
                                                 u16* __restrict__ dst,
                                                 int rows, int srows, int scols,
                                                 int dcols, int perm) {
  int idx = blockIdx.x * 256 + threadIdx.x;
  if (idx >= rows * dcols) return;
  int r = idx / dcols, c = idx - r * dcols;
  int sr = perm ? ((r & 3) * 200 + (r >> 2)) : r;
  dst[idx] = (r < srows && c < scols) ? f2bf(src[(size_t)sr * scols + c]) : (u16)0;
}

// ---------------------------------------------------------------------------
// Transpose chunk: x [B][129][600] f32 -> xTq [B][TC_][160] bf16, window t0.
// ---------------------------------------------------------------------------
__global__ __launch_bounds__(256) void transpose_k(const float* __restrict__ x,
                                                   u16* __restrict__ xTq, int t0) {
  __shared__ u16 tile[129 * 65];
  const int b = blockIdx.y;
  const int tt0 = blockIdx.x * 64;
  const int tid = threadIdx.x;
  for (int idx = tid; idx < 129 * 64; idx += 256) {
    int i = idx >> 6, tt = idx & 63;
    int t = t0 + tt0 + tt;
    tile[i * 65 + tt] = (tt0 + tt < TC_ && t < T_)
        ? f2bf(x[((size_t)b * 129 + i) * T_ + t]) : (u16)0;
  }
  __syncthreads();
  for (int idx = tid; idx < 64 * 160; idx += 256) {
    int tt = idx / 160, i = idx - tt * 160;
    if (tt0 + tt < TC_)
      xTq[((size_t)b * TC_ + tt0 + tt) * 160 + i] = (i < 129) ? tile[i * 65 + tt] : (u16)0;
  }
}

// ---------------------------------------------------------------------------
// GEMM: out = ACT(A @ W^T + bias).
// ---------------------------------------------------------------------------
template<int ASRC, int LDK, int NSRC, int NSTORE, int BPERM, int ACT, int OUTM, int CHUNK>
__global__ __launch_bounds__(256, 2) void gemm_k(
    const u16* __restrict__ A, const u16* __restrict__ W,
    const float* __restrict__ B1, const float* __restrict__ B2,
    void* __restrict__ outv, int ldout, int t0) {
  constexpr int NCH = LDK / 8;
  constexpr int KT = LDK / 32;
  __shared__ u16 la[128 * LDK];
  __shared__ float lbias[128];
  const int tid = threadIdx.x;
  const int mb = blockIdx.x, nb = blockIdx.y;

  for (int idx = tid; idx < 128 * NCH; idx += 256) {
    int row = idx / NCH, c = idx - row * NCH;
    int m = mb * 128 + row;
    size_t arow;
    if (CHUNK) {
      int b = m / TC_;
      int tt = m - b * TC_;
      arow = (size_t)b * T_ + t0 + tt;
    } else {
      arow = (size_t)m;
    }
    short8 v = (short8)0;
    if (8 * c + 8 <= ASRC)
      v = *(const short8*)(A + arow * ASRC + 8 * c);
    *(short8*)(la + row * LDK + 8 * c) = v;
  }
  if (tid < 128) {
    int p = nb * 128 + tid;
    float bv = 0.f;
    if (p < NSRC) {
      int orig = BPERM ? ((p & 3) * 200 + (p >> 2)) : p;
      bv = B1[orig];
      if (BPERM) bv += B2[orig];
    }
    lbias[tid] = bv;
  }
  __syncthreads();

  const int w = tid >> 6, l = tid & 63;
  const int quad = l >> 4, l15 = l & 15;
  const int mq = (w >> 1) * 64, nq = (w & 1) * 64;

  const u16* wrow[4];
#pragma unroll
  for (int nt = 0; nt < 4; ++nt) {
    int p = nb * 128 + nq + nt * 16 + l15;
    wrow[nt] = W + (size_t)((p < NSRC) ? p : 0) * LDK;
  }

  f32x4 acc[4][4];
#pragma unroll
  for (int i = 0; i < 4; ++i)
#pragma unroll
    for (int j = 0; j < 4; ++j) acc[i][j] = (f32x4)0.f;

#pragma unroll
  for (int kt = 0; kt < KT; ++kt) {
    const int k0 = kt * 32 + quad * 8;
    short8 bf[4];
#pragma unroll
    for (int nt = 0; nt < 4; ++nt) bf[nt] = *(const short8*)(wrow[nt] + k0);
    short8 af[4];
#pragma unroll
    for (int mt = 0; mt < 4; ++mt)
      af[mt] = *(const short8*)(la + (mq + mt * 16 + l15) * LDK + k0);
#pragma unroll
    for (int mt = 0; mt < 4; ++mt)
#pragma unroll
      for (int nt = 0; nt < 4; ++nt)
        acc[mt][nt] = __builtin_amdgcn_mfma_f32_16x16x32_bf16(af[mt], bf[nt],
                                                              acc[mt][nt], 0, 0, 0);
  }

#pragma unroll
  for (int mt = 0; mt < 4; ++mt) {
#pragma unroll
    for (int nt = 0; nt < 4; ++nt) {
#pragma unroll
      for (int r = 0; r < 4; ++r) {
        int rowl = mq + mt * 16 + quad * 4 + r;
        int coln = nq + nt * 16 + l15;
        int pg = nb * 128 + coln;
        if (pg < NSTORE) {
          float v = (pg < NSRC) ? (acc[mt][nt][r] + lbias[coln]) : 0.f;
          if (ACT == 1) v = fmaxf(v, 0.f);
          if (ACT == 2) v = sigm(v);
          size_t m = (size_t)mb * 128 + rowl;
          if (OUTM == 0) {
            ((u16*)outv)[m * (size_t)ldout + pg] = f2bf(v);
          } else {
            int b = (int)(m / T_);
            int t = (int)(m - (size_t)b * T_);
            ((float*)outv)[((size_t)b * 129 + pg) * T_ + t] = v;
          }
        }
      }
    }
  }
}

// ---------------------------------------------------------------------------
// Persistent LSTM recurrence over one time chunk [t0, t0+TC_).
// 16 waves (1024 thr) / block for 4 waves/SIMD latency hiding. 50 N-tiles
// split <=4 slots/wave. k-tiles 0..3 register-resident (64 VGPR); k-tiles
// 4,5 staged in LDS (100 KB, read-only after prologue); k-tile 6 compact
// LDS table as before. Same per-step sync structure as the verified 8-wave
// body: publish -> lgkm barrier -> reads -> plain barrier.
// ---------------------------------------------------------------------------
__device__ __forceinline__ void rec_body(const u16* __restrict__ xgq,
                                         const u16* __restrict__ whh,
                                         u16* __restrict__ hout,
                                         float* __restrict__ cst,
                                         int t0, int blk) {
  __shared__ u16 hbuf[16 * HSTR];       //   7,424 B  h[batch][unit]
  __shared__ u16 w45[50 * 2 * 512];     // 102,400 B  k-tiles 4,5 full fragments
  __shared__ u16 w6lds[50 * 128];       //  12,800 B  k-tile 6 compact (quad0)

  const int tid = threadIdx.x;
  const int w = tid >> 6, l = tid & 63;
  const int quad = l >> 4, l15 = l & 15;
  const int b0 = blk * 16;
  const int nslots = (w < 2) ? 4 : 3;   // 50 N-tiles over 16 waves

  // ---- prologue: weight caches ----
  short8 wreg[4][4];                    // k-tiles 0..3
#pragma unroll
  for (int s = 0; s < 4; ++s) {
    int tile = w + 16 * s;
    int p = tile * 16 + l15;
    int orig = (p & 3) * 200 + (p >> 2);
    const char* wbase = (const char*)whh + (size_t)orig * 400;
#pragma unroll
    for (int kk = 0; kk < 4; ++kk) {
      short8 v = (short8)0;
      if (s < nslots)
        v = *(const short8*)(wbase + kk * 64 + quad * 16);
      wreg[s][kk] = v;
    }
    if (s < nslots) {
#pragma unroll
      for (int j = 0; j < 2; ++j) {
        short8 v = *(const short8*)(wbase + (4 + j) * 64 + quad * 16);
        *(short8*)(w45 + ((size_t)tile * 2 + j) * 512 + l15 * 32 + quad * 8) = v;
      }
      if (quad == 0) {
        short8 v6 = *(const short8*)(wbase + 384);
        *(short8*)(w6lds + tile * 128 + l15 * 8) = v6;
      }
    }
  }
  for (int i = tid; i < 16 * HSTR; i += 1024) hbuf[i] = 0;

  // ---- state: slot s -> (batch l15, unit (w+16s)*4+quad) ----
  float c[4];
  u16 hreg[4];
#pragma unroll
  for (int s = 0; s < 4; ++s) { c[s] = 0.f; hreg[s] = 0; }
  if (t0 != 0) {
#pragma unroll
    for (int s = 0; s < 4; ++s)
      if (s < nslots) {
        int unit = (w + 16 * s) * 4 + quad;
        hreg[s] = hout[((size_t)(b0 + l15) * T_ + (t0 - 1)) * HID + unit];
        c[s] = cst[(size_t)(b0 + l15) * HID + unit];
      }
  }

  // per-lane xg gather base (t=0 of this chunk) + first prefetch
  const u16* xptr = xgq + (size_t)(b0 + l15) * TC_ * G4 + w * 16 + quad * 4;
  u16x4 xv[4];
#pragma unroll
  for (int s = 0; s < 4; ++s)
    xv[s] = (s < nslots) ? *(const u16x4*)(xptr + s * 256) : (u16x4)0;

  // per-lane hout base for unit stores
  u16* hptr = hout + ((size_t)(b0 + l15) * T_ + t0) * HID;

  __syncthreads();  // prologue fence (w45/w6lds + hbuf zeros visible)

  for (int t = 0; t < TC_; ++t) {
    // publish h(t-1) to LDS
#pragma unroll
    for (int s = 0; s < 4; ++s)
      if (s < nslots)
        hbuf[l15 * HSTR + (w + 16 * s) * 4 + quad] = hreg[s];
    BARRIER_LGKM();  // sync_a

    // deferred global h(t-1) store (stays in flight across barriers)
    if (t > 0) {
#pragma unroll
      for (int s = 0; s < 4; ++s)
        if (s < nslots)
          hptr[(size_t)(t - 1) * HID + (w + 16 * s) * 4 + quad] = hreg[s];
    }

    // ---- gates^T = Whh_perm @ h(t-1)^T ----
    f32x4 acc[4];
#pragma unroll
    for (int s = 0; s < 4; ++s) acc[s] = (f32x4)0.f;
#pragma unroll
    for (int kk = 0; kk < 4; ++kk) {
      short8 hf = *(const short8*)(hbuf + l15 * HSTR + kk * 32 + quad * 8);
#pragma unroll
      for (int s = 0; s < 4; ++s)
        if (s < nslots)
          acc[s] = __builtin_amdgcn_mfma_f32_16x16x32_bf16(wreg[s][kk], hf, acc[s], 0, 0, 0);
    }
#pragma unroll
    for (int j = 0; j < 2; ++j) {  // k-tiles 4,5 from LDS
      short8 hf = *(const short8*)(hbuf + l15 * HSTR + (4 + j) * 32 + quad * 8);
#pragma unroll
      for (int s = 0; s < 4; ++s)
        if (s < nslots) {
          short8 wz = *(const short8*)(w45 + ((size_t)(w + 16 * s) * 2 + j) * 512
                                       + l15 * 32 + quad * 8);
          acc[s] = __builtin_amdgcn_mfma_f32_16x16x32_bf16(wz, hf, acc[s], 0, 0, 0);
        }
    }
    {  // tail k-tile 6: h cols 192..199 real, 200..223 zero-padded
      short8 hf = *(const short8*)(hbuf + l15 * HSTR + 192 + quad * 8);
#pragma unroll
      for (int s = 0; s < 4; ++s)
        if (s < nslots) {
          short8 wz = (short8)0;
          if (quad == 0)
            wz = *(const short8*)(w6lds + (w + 16 * s) * 128 + l15 * 8);
          acc[s] = __builtin_amdgcn_mfma_f32_16x16x32_bf16(wz, hf, acc[s], 0, 0, 0);
        }
    }

    // ---- lane-local cell update: acc[s][0..3] = i,f,g,o pre-acts ----
#pragma unroll
    for (int s = 0; s < 4; ++s) {
      if (s < nslots) {
        float vi = acc[s][0] + bf2f(xv[s][0]);
        float vf = acc[s][1] + bf2f(xv[s][1]);
        float vg = acc[s][2] + bf2f(xv[s][2]);
        float vo = acc[s][3] + bf2f(xv[s][3]);
        float iv = sigm(vi);
        float fv = sigm(vf);
        float gv = 2.f * sigm(2.f * vg) - 1.f;  // tanh
        float ov = sigm(vo);
        float cn = fv * c[s] + iv * gv;
        c[s] = cn;
        float th = 2.f * sigm(2.f * cn) - 1.f;
        hreg[s] = f2bf(ov * th);
      }
    }

    // prefetch xg(t+1) into the (just-consumed) xv regs
    if (t + 1 < TC_) {
      const u16* xp = xptr + (size_t)(t + 1) * G4;
#pragma unroll
      for (int s = 0; s < 4; ++s)
        if (s < nslots) xv[s] = *(const u16x4*)(xp + s * 256);
    }
    BARRIER_ONLY();  // sync_b: all hbuf reads already register-consumed
  }

  // final h(t0+TC_-1) + carry state
#pragma unroll
  for (int s = 0; s < 4; ++s)
    if (s < nslots) {
      int unit = (w + 16 * s) * 4 + quad;
      hptr[(size_t)(TC_ - 1) * HID + unit] = hreg[s];
      cst[(size_t)(b0 + l15) * HID + unit] = c[s];
    }
}

// Fused dual-group recurrence: blocks [0,nA) run param set A (layer-1 chunk),
// blocks [nA,grid) run set B (layer-2 chunk) on other CUs, concurrently.
__global__ __launch_bounds__(1024) void recp_k(
    const u16* __restrict__ xgA, const u16* __restrict__ whhA,
    u16* __restrict__ hA, float* __restrict__ cstA, int t0A,
    const u16* __restrict__ xgB, const u16* __restrict__ whhB,
    u16* __restrict__ hB, float* __restrict__ cstB, int t0B, int nA) {
  const int bb = blockIdx.x;
  const u16* xg; const u16* whh; u16* ho; float* cs; int t0, blk;
  if (bb < nA) { xg = xgA; whh = whhA; ho = hA; cs = cstA; t0 = t0A; blk = bb; }
  else         { xg = xgB; whh = whhB; ho = hB; cs = cstB; t0 = t0B; blk = bb - nA; }
  rec_body(xg, whh, ho, cs, t0, blk);
}

// ---------------------------------------------------------------------------
extern "C" void kernel_launch(void* const* d_in, const int* in_sizes, int n_in,
                              void* d_out, int out_size, void* d_ws, size_t ws_size,
                              hipStream_t stream) {
  (void)in_sizes; (void)n_in; (void)out_size; (void)ws_size;
  const float* x     = (const float*)d_in[0];
  const float* w_ih1 = (const float*)d_in[1];
  const float* w_hh1 = (const float*)d_in[2];
  const float* b_ih1 = (const float*)d_in[3];
  const float* b_hh1 = (const float*)d_in[4];
  const float* w_ih2 = (const float*)d_in[5];
  const float* w_hh2 = (const float*)d_in[6];
  const float* b_ih2 = (const float*)d_in[7];
  const float* b_hh2 = (const float*)d_in[8];
  const float* fc1_w = (const float*)d_in[9];
  const float* fc1_b = (const float*)d_in[10];
  const float* fc2_w = (const float*)d_in[11];
  const float* fc2_b = (const float*)d_in[12];
  float* out = (float*)d_out;

  // workspace layout (bytes, 16-aligned); total ~192.2 MB
  char* ws = (char*)d_ws;
  u16*   xgA   = (u16*)(ws);                     //  30,720,000  [256][75][800]
  u16*   xgB   = (u16*)(ws + 30720000LL);        //  30,720,000  [256][75][800]
  u16*   h1    = (u16*)(ws + 61440000LL);        //  61,440,000  [256][600][200]
  u16*   h2    = (u16*)(ws + 122880000LL);       //  61,440,000
  u16*   xTq   = (u16*)(ws + 184320000LL);       //   6,144,000  [256][75][160]
  float* cst1  = (float*)(ws + 190464000LL);     //     204,800  [256][200] f32
  float* cst2  = (float*)(ws + 190668800LL);     //     204,800
  u16*   wp1   = (u16*)(ws + 190873600LL);       //     256,000  [800][160]
  u16*   wp2   = (u16*)(ws + 191129600LL);       //     358,400  [800][224]
  u16*   fc1p  = (u16*)(ws + 191488000LL);       //      57,792  [129][224]
  u16*   fc2p  = (u16*)(ws + 191545792LL);       //      41,280  [129][160]
  u16*   whh1c = (u16*)(ws + 191587072LL);       //     320,000  [800][200]
  u16*   whh2c = (u16*)(ws + 191907072LL);       //     320,000  [800][200]
  u16*   y1    = h1;                             // reuse after layer-2 GEMMs

  padperm_k<<<(800 * 160 + 255) / 256, 256, 0, stream>>>(w_ih1, wp1, 800, 800, 129, 160, 1);
  padperm_k<<<(800 * 224 + 255) / 256, 256, 0, stream>>>(w_ih2, wp2, 800, 800, 200, 224, 1);
  padperm_k<<<(129 * 224 + 255) / 256, 256, 0, stream>>>(fc1_w, fc1p, 129, 129, 200, 224, 0);
  padperm_k<<<(129 * 160 + 255) / 256, 256, 0, stream>>>(fc2_w, fc2p, 129, 129, 129, 160, 0);
  padperm_k<<<(800 * 200 + 255) / 256, 256, 0, stream>>>(w_hh1, whh1c, 800, 800, 200, 200, 0);
  padperm_k<<<(800 * 200 + 255) / 256, 256, 0, stream>>>(w_hh2, whh2c, 800, 800, 200, 200, 0);

  // ---- software pipeline: rec1(c_{i+1}) runs concurrently with rec2(c_i) ----
  // stage 0: layer-1 chunk 0 alone
  transpose_k<<<dim3(2, 256), 256, 0, stream>>>(x, xTq, 0);
  gemm_k<160, 160, 800, 800, 1, 0, 0, 0>
      <<<dim3(150, 7), 256, 0, stream>>>(xTq, wp1, b_ih1, b_hh1, xgA, 800, 0);
  recp_k<<<dim3(16), 1024, 0, stream>>>(xgA, whh1c, h1, cst1, 0,
                                        xgA, whh1c, h1, cst1, 0, 16);

  // stages 1..7: fused (layer-1 chunk i+1 || layer-2 chunk i)
  for (int i = 0; i < 7; ++i) {
    const int tA = (i + 1) * TC_;
    const int tB = i * TC_;
    transpose_k<<<dim3(2, 256), 256, 0, stream>>>(x, xTq, tA);
    gemm_k<160, 160, 800, 800, 1, 0, 0, 0>
        <<<dim3(150, 7), 256, 0, stream>>>(xTq, wp1, b_ih1, b_hh1, xgA, 800, 0);
    gemm_k<200, 224, 800, 800, 1, 0, 0, 1>
        <<<dim3(150, 7), 256, 0, stream>>>(h1, wp2, b_ih2, b_hh2, xgB, 800, tB);
    recp_k<<<dim3(32), 1024, 0, stream>>>(xgA, whh1c, h1, cst1, tA,
                                          xgB, whh2c, h2, cst2, tB, 16);
  }

  // stage 8: layer-2 chunk 7 alone
  gemm_k<200, 224, 800, 800, 1, 0, 0, 1>
      <<<dim3(150, 7), 256, 0, stream>>>(h1, wp2, b_ih2, b_hh2, xgB, 800, 7 * TC_);
  recp_k<<<dim3(16), 1024, 0, stream>>>(xgA, whh1c, h1, cst1, 0,
                                        xgB, whh2c, h2, cst2, 7 * TC_, 0);

  // y1 = relu(h2 @ fc1^T + b)
  gemm_k<200, 224, 129, 144, 0, 1, 0, 0>
      <<<dim3(1200, 2), 256, 0, stream>>>(h2, fc1p, fc1_b, fc1_b, y1, 144, 0);
  // out = sigmoid(y1 @ fc2^T + b), f32 scatter to [B][129][T]
  gemm_k<144, 160, 129, 129, 0, 2, 1, 0>
      <<<dim3(1200, 2), 256, 0, stream>>>(y1, fc2p, fc2_b, fc2_b, out, 0, 0);
}